// Round 2
// baseline (728.320 us; speedup 1.0000x reference)
//
#include <hip/hip_runtime.h>
#include <hip/hip_bf16.h>
#include <stdint.h>

#define NTOK 145
#define MTOK 144
#define CDIM 512
#define NHEAD 8
#define HD 64
#define NWIN 4
#define BWIN 512
#define MROWS (BWIN*NTOK)   // 74240 = 290*256

typedef short short8 __attribute__((ext_vector_type(8)));
typedef float f32x4 __attribute__((ext_vector_type(4)));

__device__ __forceinline__ uint16_t f2bf(float f) {
  union { float f; uint32_t u; } x; x.f = f;
  uint32_t r = x.u + 0x7FFFu + ((x.u >> 16) & 1u);
  return (uint16_t)(r >> 16);
}
__device__ __forceinline__ float bf2f(uint16_t u) {
  union { uint32_t u; float f; } x; x.u = ((uint32_t)u) << 16; return x.f;
}
__device__ __forceinline__ uint32_t pack2(float a, float b) {
  return (uint32_t)f2bf(a) | ((uint32_t)f2bf(b) << 16);
}

// async global->LDS, 16B per lane, LDS dest = wave-uniform base + lane*16
#define GLL(gp, lp) __builtin_amdgcn_global_load_lds( \
    (const __attribute__((address_space(1))) uint32_t*)(gp), \
    (__attribute__((address_space(3))) uint32_t*)(lp), 16, 0, 0)

// ---------------- cast x -> bf16 ----------------
__global__ __launch_bounds__(256) void cast_x(const float* __restrict__ x,
                                              uint16_t* __restrict__ xb) {
  size_t id = ((size_t)blockIdx.x*256 + threadIdx.x)*8;
  float4 a = *(const float4*)(x+id), c = *(const float4*)(x+id+4);
  uint4 o = make_uint4(pack2(a.x,a.y), pack2(a.z,a.w), pack2(c.x,c.y), pack2(c.z,c.w));
  *(uint4*)(xb+id) = o;
}

// ---------------- prep: weight casts + combined logit-bias table ----------------
__global__ void prep_kernel(const float* __restrict__ rpb,
                            const float* __restrict__ Wq, const float* __restrict__ bq,
                            const float* __restrict__ Wk, const float* __restrict__ bk,
                            const float* __restrict__ Wv, const float* __restrict__ bv,
                            const float* __restrict__ Wo, const float* __restrict__ mask,
                            uint16_t* __restrict__ wqkv, uint16_t* __restrict__ wo,
                            float* __restrict__ bqkv, float* __restrict__ ltab) {
  int id = blockIdx.x * 256 + threadIdx.x;
  const int A = 1536*512, B = 512*512, C2 = 1536, E = 4*8*145*160;
  if (id < A) {
    int n = id >> 9, k = id & 511;
    const float* W = (n < 512) ? Wq : (n < 1024) ? Wk : Wv;
    wqkv[id] = f2bf(W[(size_t)(n & 511)*512 + k]);
  } else if ((id -= A) < B) {
    wo[id] = f2bf(Wo[id]);
  } else if ((id -= B) < C2) {
    bqkv[id] = (id < 512) ? bq[id] : (id < 1024) ? bk[id-512] : bv[id-1024];
  } else if ((id -= C2) < E) {
    int nw = id / (8*145*160);
    int r2 = id % (8*145*160);
    int h = r2 / (145*160);
    int r3 = r2 % (145*160);
    int i = r3 / 160, j = r3 % 160;
    float v = 0.f;
    if (j < 145) v = mask[(nw*145 + i)*145 + j];
    if (i < 144 && j < 144) {
      int rel = (i/12 - j/12 + 11) * 23 + (i%12 - j%12 + 11);
      v += rpb[rel*8 + h];
    }
    ltab[id] = v;
  }
}

// ---------------- GEMM 1: qkv projection ----------------
// 256x256 tile, BK=32, 8 waves (2M x 4N), quad-buffered LDS, depth-2 counted-vmcnt
// pipeline: loads for K-tile kt+1/kt+2 stay in flight across barriers (T3+T4).
__global__ __launch_bounds__(512, 2) void gemm_qkv(
    const uint16_t* __restrict__ xb, const uint16_t* __restrict__ wqkv,
    const float* __restrict__ bqkv,
    uint16_t* __restrict__ qb, uint16_t* __restrict__ kb, uint16_t* __restrict__ vb) {
  __shared__ __align__(16) uint16_t As[4*256*32];
  __shared__ __align__(16) uint16_t Bs[4*256*32];
  int bid = blockIdx.x;
  int mb, nb;
  // 48-bid groups: 8 mb (one per XCD) x 6 nb -> the 6 sharers of an A-panel co-XCD
  if (bid < 1728) { int g = bid / 48, r = bid % 48; mb = g*8 + (r & 7); nb = r >> 3; }
  else            { int r = bid - 1728;             mb = 288 + (r & 1); nb = r >> 1; }
  int tid = threadIdx.x, lane = tid & 63, w = tid >> 6;
  int wm = w >> 2, wn = w & 3;
  int lm = lane & 15, lq = lane >> 4;

  // staging: wave w covers rows w*32..w*32+31; lane -> (row=l>>2, 16B slot=l&3)
  int srow = lane >> 2, scol = (lane & 3) * 8;
  const uint16_t* agp = xb   + (size_t)(mb*256 + w*32 + srow)*512 + scol;
  const uint16_t* bgp = wqkv + (size_t)(nb*256 + w*32 + srow)*512 + scol;

  f32x4 acc[8][4];
#pragma unroll
  for (int a = 0; a < 8; a++)
#pragma unroll
    for (int b = 0; b < 4; b++) acc[a][b] = (f32x4){0.f,0.f,0.f,0.f};

  #define STAGE_QKV(slot, kt) { \
    uint16_t* Ad = &As[(slot)*8192 + (w*32)*32]; \
    uint16_t* Bd = &Bs[(slot)*8192 + (w*32)*32]; \
    GLL(agp + (kt)*32,           Ad); \
    GLL(agp + (kt)*32 + 16*512,  Ad + 16*32); \
    GLL(bgp + (kt)*32,           Bd); \
    GLL(bgp + (kt)*32 + 16*512,  Bd + 16*32); \
  }

  #define COMPUTE_QKV(slot) { \
    const uint16_t* Ab = &As[(slot)*8192 + (wm*128 + lm)*32 + lq*8]; \
    const uint16_t* Bb = &Bs[(slot)*8192 + (wn*64  + lm)*32 + lq*8]; \
    short8 a[8], b[4]; \
    _Pragma("unroll") \
    for (int mr = 0; mr < 8; mr++) a[mr] = *(const short8*)&Ab[mr*16*32]; \
    _Pragma("unroll") \
    for (int nr = 0; nr < 4; nr++) b[nr] = *(const short8*)&Bb[nr*16*32]; \
    __builtin_amdgcn_s_setprio(1); \
    _Pragma("unroll") \
    for (int mr = 0; mr < 8; mr++) \
      _Pragma("unroll") \
      for (int nr = 0; nr < 4; nr++) \
        acc[mr][nr] = __builtin_amdgcn_mfma_f32_16x16x32_bf16(a[mr], b[nr], acc[mr][nr], 0, 0, 0); \
    __builtin_amdgcn_s_setprio(0); \
  }

  STAGE_QKV(0, 0);
  STAGE_QKV(1, 1);
  for (int kt = 0; kt < 15; kt++) {
    // wait own stage(kt) loads (4 oldest); stage(kt+1) stays in flight
    asm volatile("s_waitcnt vmcnt(4)" ::: "memory");
    __builtin_amdgcn_s_barrier();
    __builtin_amdgcn_sched_barrier(0);
    if (kt < 14) STAGE_QKV((kt + 2) & 3, kt + 2);
    COMPUTE_QKV(kt & 3);
  }
  asm volatile("s_waitcnt vmcnt(0)" ::: "memory");
  __builtin_amdgcn_s_barrier();
  __builtin_amdgcn_sched_barrier(0);
  COMPUTE_QKV(3);   // kt = 15

  #undef STAGE_QKV
  #undef COMPUTE_QKV

#pragma unroll
  for (int nr = 0; nr < 4; nr++) {
    int n = nb*256 + wn*64 + nr*16 + lm;
    float bias = bqkv[n];
    int which = nb >> 1;   // 0:q 1:k 2:v (tiles of 256 don't cross 512 boundaries)
    uint16_t* dst = (which == 0) ? qb : (which == 1) ? kb : vb;
    int c = n & 511;
    int hh = c >> 6, dd = c & 63;
#pragma unroll
    for (int mr = 0; mr < 8; mr++) {
#pragma unroll
      for (int r = 0; r < 4; r++) {
        int m = mb*256 + wm*128 + mr*16 + lq*4 + r;
        int bw = m / 145, nl = m - bw*145;
        dst[((size_t)(bw*8 + hh)*145 + nl)*64 + dd] = f2bf(acc[mr][nr][r] + bias);
      }
    }
  }
}

// ---------------- attention: S=QK^T (+ltab via C-operand), softmax, P*V ----------------
__global__ __launch_bounds__(256, 3) void attn_kernel(
    const uint16_t* __restrict__ qb, const uint16_t* __restrict__ kb,
    const uint16_t* __restrict__ vb, const float* __restrict__ ltab,
    float* __restrict__ glog, uint16_t* __restrict__ attn_out) {
  __shared__ __align__(16) uint16_t P[80*168];
  __shared__ __align__(16) uint16_t vt[64*168];
  int bid = blockIdx.x;
  int half = bid & 1;
  int h = (bid >> 1) & 7;
  int b_ = bid >> 4;
  int nw = b_ & 3;
  int tid = threadIdx.x, lane = tid & 63, w = tid >> 6;
  int lm = lane & 15, lq = lane >> 4;
  const size_t hbase = ((size_t)(b_*8 + h)) * (145*64);
  const uint16_t* qp = qb + hbase;
  const uint16_t* kp = kb + hbase;
  const uint16_t* vp = vb + hbase;
  const float* ltp = ltab + (size_t)(nw*8 + h)*(145*160);

  for (int c = tid; c < 1160; c += 256) {
    int j = c >> 3, d0 = (c & 7) * 8;
    uint16_t tmp[8];
    *(uint4*)tmp = *(const uint4*)(vp + (size_t)j*64 + d0);
#pragma unroll
    for (int t = 0; t < 8; t++) vt[(d0 + t)*168 + j] = tmp[t];
  }
  for (int c = tid; c < 960; c += 256)
    vt[(c/15)*168 + 145 + (c%15)] = 0;

  for (int ltile = w; ltile < 5; ltile += 4) {
    int gt = half*5 + ltile;
    f32x4 acc[10];
#pragma unroll
    for (int nt = 0; nt < 10; nt++) {
#pragma unroll
      for (int r = 0; r < 4; r++) {
        int i = gt*16 + lq*4 + r; if (i > 144) i = 144;
        acc[nt][r] = 8.0f * ltp[i*160 + nt*16 + lm];
      }
    }
    int iq = gt*16 + lm; if (iq > 144) iq = 144;
#pragma unroll
    for (int ks = 0; ks < 2; ks++) {
      short8 afr = *(const short8*)(qp + (size_t)iq*64 + ks*32 + lq*8);
#pragma unroll
      for (int nt = 0; nt < 10; nt++) {
        int j = nt*16 + lm; if (j > 144) j = 144;
        short8 bfr = *(const short8*)(kp + (size_t)j*64 + ks*32 + lq*8);
        acc[nt] = __builtin_amdgcn_mfma_f32_16x16x32_bf16(afr, bfr, acc[nt], 0, 0, 0);
      }
    }
    if (gt == 9) {
      if (lq == 0) {
#pragma unroll
        for (int nt = 0; nt < 10; nt++) {
          int j = nt*16 + lm;
          if (j < 145)
            glog[(size_t)(b_*8 + h)*145 + j] = acc[nt][0]*0.125f;
        }
      }
    } else {
#pragma unroll
      for (int r = 0; r < 4; r++) {
        int prow = ltile*16 + lq*4 + r;
        float mx = -3.0e38f;
#pragma unroll
        for (int nt = 0; nt < 10; nt++) {
          int j = nt*16 + lm;
          float t = acc[nt][r]*0.125f;
          if (j >= 145) t = -3.0e38f;
          acc[nt][r] = t;
          mx = fmaxf(mx, t);
        }
#pragma unroll
        for (int off = 1; off < 16; off <<= 1) mx = fmaxf(mx, __shfl_xor(mx, off));
        float sum = 0.f;
#pragma unroll
        for (int nt = 0; nt < 10; nt++) {
          int j = nt*16 + lm;
          float p = (j < 145) ? __expf(acc[nt][r] - mx) : 0.f;
          acc[nt][r] = p; sum += p;
        }
#pragma unroll
        for (int off = 1; off < 16; off <<= 1) sum += __shfl_xor(sum, off);
        float rs = __builtin_amdgcn_rcpf(sum);
#pragma unroll
        for (int nt = 0; nt < 10; nt++)
          P[prow*168 + nt*16 + lm] = f2bf(acc[nt][r] * rs);
      }
    }
  }
  __syncthreads();

  int npv = 5 - half;
  f32x4 oacc[5];
#pragma unroll
  for (int mt = 0; mt < 5; mt++) oacc[mt] = (f32x4){0.f,0.f,0.f,0.f};
#pragma unroll
  for (int ks = 0; ks < 5; ks++) {
    short8 bfr = *(const short8*)&vt[(w*16 + lm)*168 + ks*32 + lq*8];
#pragma unroll
    for (int mt = 0; mt < 5; mt++) {
      if (mt < npv) {
        short8 afr = *(const short8*)&P[(mt*16 + lm)*168 + ks*32 + lq*8];
        oacc[mt] = __builtin_amdgcn_mfma_f32_16x16x32_bf16(afr, bfr, oacc[mt], 0, 0, 0);
      }
    }
  }
#pragma unroll
  for (int mt = 0; mt < 5; mt++) {
    if (mt < npv) {
#pragma unroll
      for (int r = 0; r < 4; r++) {
        int i = half*80 + mt*16 + lq*4 + r;
        attn_out[((size_t)b_*145 + i)*512 + h*64 + w*16 + lm] = f2bf(oacc[mt][r]);
      }
    }
  }
}

// ---------------- gx: global-token redistribution (4 waves) ----------------
__global__ __launch_bounds__(256) void gx_kernel(
    const float* __restrict__ glog, const uint16_t* __restrict__ vb,
    uint16_t* __restrict__ attn_out) {
  int bid = blockIdx.x;           // b*8 + h
  int b = bid >> 3, h = bid & 7;
  int tid = threadIdx.x, lane = tid & 63, w = tid >> 6;
  __shared__ float lg[580];
  __shared__ float pl[576];
  __shared__ float sred[8];
  __shared__ float sacc[256];
  for (int t = tid; t < 580; t += 256) {
    int nwi = t / 145, j = t - nwi*145;
    lg[t] = glog[(size_t)((b*4 + nwi)*8 + h)*145 + j];
  }
  __syncthreads();
  float g2 = 0.25f*(lg[144] + lg[289] + lg[434] + lg[579]);
  float mx = g2;
  for (int t = tid; t < 576; t += 256) {
    int nwi = t / 144, j = t - nwi*144;
    mx = fmaxf(mx, lg[nwi*145 + j]);
  }
#pragma unroll
  for (int off = 1; off < 64; off <<= 1) mx = fmaxf(mx, __shfl_xor(mx, off));
  if (lane == 0) sred[w] = mx;
  __syncthreads();
  mx = fmaxf(fmaxf(sred[0], sred[1]), fmaxf(sred[2], sred[3]));
  float sum = 0.f;
  for (int t = tid; t < 576; t += 256) {
    int nwi = t / 144, j = t - nwi*144;
    float p = __expf(lg[nwi*145 + j] - mx);
    pl[t] = p; sum += p;
  }
#pragma unroll
  for (int off = 1; off < 64; off <<= 1) sum += __shfl_xor(sum, off);
  if (lane == 0) sred[4 + w] = sum;
  __syncthreads();
  sum = (sred[4] + sred[5]) + (sred[6] + sred[7]);
  float p2 = __expf(g2 - mx);
  float rs = __builtin_amdgcn_rcpf(sum + p2);
  const uint16_t* vp = vb + (size_t)((b*4 + w)*8 + h)*(145*64);
  float acc = 0.f;
  int d = lane;
#pragma unroll 4
  for (int j = 0; j < 144; j++)
    acc += pl[w*144 + j] * bf2f(vp[j*64 + d]);
  acc += p2 * bf2f(vp[144*64 + d]);
  sacc[tid] = acc;
  __syncthreads();
  if (w == 0) {
    float tot = (sacc[lane] + sacc[64 + lane]) + (sacc[128 + lane] + sacc[192 + lane]);
    uint16_t o = f2bf(tot * rs);
    for (int nwi = 0; nwi < 4; nwi++)
      attn_out[((size_t)(b*4 + nwi)*145 + 144)*512 + h*64 + d] = o;
  }
}

// ---------------- GEMM 2: output projection (same pipelined core) ----------------
__global__ __launch_bounds__(512, 2) void gemm_out(
    const uint16_t* __restrict__ A, const uint16_t* __restrict__ wo,
    const float* __restrict__ bo, float* __restrict__ out) {
  __shared__ __align__(16) uint16_t As[4*256*32];
  __shared__ __align__(16) uint16_t Bs[4*256*32];
  int bid = blockIdx.x;
  int mb, nb;
  if (bid < 576) { int g = bid / 16, r = bid % 16; mb = g*8 + (r & 7); nb = r >> 3; }
  else           { int r = bid - 576;              mb = 288 + (r & 1); nb = r >> 1; }
  int tid = threadIdx.x, lane = tid & 63, w = tid >> 6;
  int wm = w >> 2, wn = w & 3;
  int lm = lane & 15, lq = lane >> 4;

  int srow = lane >> 2, scol = (lane & 3) * 8;
  const uint16_t* agp = A  + (size_t)(mb*256 + w*32 + srow)*512 + scol;
  const uint16_t* bgp = wo + (size_t)(nb*256 + w*32 + srow)*512 + scol;

  f32x4 acc[8][4];
#pragma unroll
  for (int a = 0; a < 8; a++)
#pragma unroll
    for (int b = 0; b < 4; b++) acc[a][b] = (f32x4){0.f,0.f,0.f,0.f};

  #define STAGE_O(slot, kt) { \
    uint16_t* Ad = &As[(slot)*8192 + (w*32)*32]; \
    uint16_t* Bd = &Bs[(slot)*8192 + (w*32)*32]; \
    GLL(agp + (kt)*32,           Ad); \
    GLL(agp + (kt)*32 + 16*512,  Ad + 16*32); \
    GLL(bgp + (kt)*32,           Bd); \
    GLL(bgp + (kt)*32 + 16*512,  Bd + 16*32); \
  }

  #define COMPUTE_O(slot) { \
    const uint16_t* Ab = &As[(slot)*8192 + (wm*128 + lm)*32 + lq*8]; \
    const uint16_t* Bb = &Bs[(slot)*8192 + (wn*64  + lm)*32 + lq*8]; \
    short8 a[8], b[4]; \
    _Pragma("unroll") \
    for (int mr = 0; mr < 8; mr++) a[mr] = *(const short8*)&Ab[mr*16*32]; \
    _Pragma("unroll") \
    for (int nr = 0; nr < 4; nr++) b[nr] = *(const short8*)&Bb[nr*16*32]; \
    __builtin_amdgcn_s_setprio(1); \
    _Pragma("unroll") \
    for (int mr = 0; mr < 8; mr++) \
      _Pragma("unroll") \
      for (int nr = 0; nr < 4; nr++) \
        acc[mr][nr] = __builtin_amdgcn_mfma_f32_16x16x32_bf16(a[mr], b[nr], acc[mr][nr], 0, 0, 0); \
    __builtin_amdgcn_s_setprio(0); \
  }

  STAGE_O(0, 0);
  STAGE_O(1, 1);
  for (int kt = 0; kt < 15; kt++) {
    asm volatile("s_waitcnt vmcnt(4)" ::: "memory");
    __builtin_amdgcn_s_barrier();
    __builtin_amdgcn_sched_barrier(0);
    if (kt < 14) STAGE_O((kt + 2) & 3, kt + 2);
    COMPUTE_O(kt & 3);
  }
  asm volatile("s_waitcnt vmcnt(0)" ::: "memory");
  __builtin_amdgcn_s_barrier();
  __builtin_amdgcn_sched_barrier(0);
  COMPUTE_O(3);

  #undef STAGE_O
  #undef COMPUTE_O

#pragma unroll
  for (int nr = 0; nr < 4; nr++) {
    int n = nb*256 + wn*64 + nr*16 + lm;
    float bias = bo[n];
#pragma unroll
    for (int mr = 0; mr < 8; mr++) {
#pragma unroll
      for (int r = 0; r < 4; r++) {
        int m = mb*256 + wm*128 + mr*16 + lq*4 + r;
        out[(size_t)m*512 + n] = acc[mr][nr][r] + bias;
      }
    }
  }
}

// ---------------- launch ----------------
extern "C" void kernel_launch(void* const* d_in, const int* in_sizes, int n_in,
                              void* d_out, int out_size, void* d_ws, size_t ws_size,
                              hipStream_t stream) {
  const float* x    = (const float*)d_in[0];
  const float* mask = (const float*)d_in[1];
  const float* rpb  = (const float*)d_in[2];
  const float* Wq   = (const float*)d_in[3];
  const float* bq   = (const float*)d_in[4];
  const float* Wk   = (const float*)d_in[5];
  const float* bk   = (const float*)d_in[6];
  const float* Wv   = (const float*)d_in[7];
  const float* bv   = (const float*)d_in[8];
  const float* Wo   = (const float*)d_in[9];
  const float* bo   = (const float*)d_in[10];

  uint8_t* ws = (uint8_t*)d_ws;
  size_t off = 0;
  auto alloc = [&](size_t bytes) -> void* {
    void* p = ws + off; off += (bytes + 255) & ~(size_t)255; return p;
  };
  uint16_t* wqkv   = (uint16_t*)alloc((size_t)1536*512*2);
  uint16_t* wo     = (uint16_t*)alloc((size_t)512*512*2);
  float*    bqkv   = (float*)alloc(1536*4);
  float*    ltab   = (float*)alloc((size_t)4*8*145*160*4);
  float*    glog   = (float*)alloc((size_t)512*8*145*4);
  uint16_t* xb     = (uint16_t*)alloc((size_t)MROWS*512*2);
  uint16_t* qb     = (uint16_t*)alloc((size_t)MROWS*512*2);
  uint16_t* kb     = (uint16_t*)alloc((size_t)MROWS*512*2);
  uint16_t* vb     = (uint16_t*)alloc((size_t)MROWS*512*2);
  uint16_t* attn   = (uint16_t*)alloc((size_t)MROWS*512*2);

  cast_x<<<18560, 256, 0, stream>>>(x, xb);
  prep_kernel<<<7002, 256, 0, stream>>>(rpb, Wq, bq, Wk, bk, Wv, bv, Wo, mask,
                                        wqkv, wo, bqkv, ltab);
  gemm_qkv<<<1740, 512, 0, stream>>>(xb, wqkv, bqkv, qb, kb, vb);
  attn_kernel<<<8192, 256, 0, stream>>>(qb, kb, vb, ltab, glog, attn);
  gx_kernel<<<1024, 256, 0, stream>>>(glog, vb, attn);
  gemm_out<<<580, 512, 0, stream>>>(attn, wo, bo, (float*)d_out);
}

// Round 3
// 720.085 us; speedup vs baseline: 1.0114x; 1.0114x over previous
//
#include <hip/hip_runtime.h>
#include <hip/hip_bf16.h>
#include <stdint.h>

#define NTOK 145
#define MTOK 144
#define CDIM 512
#define NHEAD 8
#define HD 64
#define NWIN 4
#define BWIN 512
#define MROWS (BWIN*NTOK)   // 74240 = 290*256

typedef short short8 __attribute__((ext_vector_type(8)));
typedef float f32x4 __attribute__((ext_vector_type(4)));

__device__ __forceinline__ uint16_t f2bf(float f) {
  union { float f; uint32_t u; } x; x.f = f;
  uint32_t r = x.u + 0x7FFFu + ((x.u >> 16) & 1u);
  return (uint16_t)(r >> 16);
}
__device__ __forceinline__ float bf2f(uint16_t u) {
  union { uint32_t u; float f; } x; x.u = ((uint32_t)u) << 16; return x.f;
}
__device__ __forceinline__ uint32_t pack2(float a, float b) {
  return (uint32_t)f2bf(a) | ((uint32_t)f2bf(b) << 16);
}

// async global->LDS, 16B per lane, LDS dest = wave-uniform base + lane*16
#define GLL(gp, lp) __builtin_amdgcn_global_load_lds( \
    (const __attribute__((address_space(1))) uint32_t*)(gp), \
    (__attribute__((address_space(3))) uint32_t*)(lp), 16, 0, 0)

// ---------------- cast x -> bf16 ----------------
__global__ __launch_bounds__(256) void cast_x(const float* __restrict__ x,
                                              uint16_t* __restrict__ xb) {
  size_t id = ((size_t)blockIdx.x*256 + threadIdx.x)*8;
  float4 a = *(const float4*)(x+id), c = *(const float4*)(x+id+4);
  uint4 o = make_uint4(pack2(a.x,a.y), pack2(a.z,a.w), pack2(c.x,c.y), pack2(c.z,c.w));
  *(uint4*)(xb+id) = o;
}

// ---------------- prep: weight casts + combined logit-bias table ----------------
__global__ void prep_kernel(const float* __restrict__ rpb,
                            const float* __restrict__ Wq, const float* __restrict__ bq,
                            const float* __restrict__ Wk, const float* __restrict__ bk,
                            const float* __restrict__ Wv, const float* __restrict__ bv,
                            const float* __restrict__ Wo, const float* __restrict__ mask,
                            uint16_t* __restrict__ wqkv, uint16_t* __restrict__ wo,
                            float* __restrict__ bqkv, float* __restrict__ ltab) {
  int id = blockIdx.x * 256 + threadIdx.x;
  const int A = 1536*512, B = 512*512, C2 = 1536, E = 4*8*145*160;
  if (id < A) {
    int n = id >> 9, k = id & 511;
    const float* W = (n < 512) ? Wq : (n < 1024) ? Wk : Wv;
    wqkv[id] = f2bf(W[(size_t)(n & 511)*512 + k]);
  } else if ((id -= A) < B) {
    wo[id] = f2bf(Wo[id]);
  } else if ((id -= B) < C2) {
    bqkv[id] = (id < 512) ? bq[id] : (id < 1024) ? bk[id-512] : bv[id-1024];
  } else if ((id -= C2) < E) {
    int nw = id / (8*145*160);
    int r2 = id % (8*145*160);
    int h = r2 / (145*160);
    int r3 = r2 % (145*160);
    int i = r3 / 160, j = r3 % 160;
    float v = 0.f;
    if (j < 145) v = mask[(nw*145 + i)*145 + j];
    if (i < 144 && j < 144) {
      int rel = (i/12 - j/12 + 11) * 23 + (i%12 - j%12 + 11);
      v += rpb[rel*8 + h];
    }
    ltab[id] = v;
  }
}

// ---------------- GEMM 1: qkv projection ----------------
// 256x256 tile, BK=32, 8 waves, quad-buffered LDS, depth-2 counted-vmcnt pipeline.
// OPERAND-SWAPPED: A-operand = weights (rows = n), B-operand = x (rows = m).
// -> C col(lane) = token, C rows(regs) = 4 consecutive d -> packed 8B stores.
// LDS XOR-swizzle (T2): linear GLL dest + pre-swizzled global src + swizzled ds_read.
__global__ __launch_bounds__(512, 2) void gemm_qkv(
    const uint16_t* __restrict__ xb, const uint16_t* __restrict__ wqkv,
    const float* __restrict__ bqkv,
    uint16_t* __restrict__ qb, uint16_t* __restrict__ kb, uint16_t* __restrict__ vb) {
  __shared__ __align__(16) uint16_t As[4*256*32];   // x tile (B-operand rows)
  __shared__ __align__(16) uint16_t Bs[4*256*32];   // w tile (A-operand rows)
  int bid = blockIdx.x;
  int mb, nb;
  // 48-bid groups: 8 mb (one per XCD) x 6 nb -> the 6 sharers of an x-panel co-XCD
  if (bid < 1728) { int g = bid / 48, r = bid % 48; mb = g*8 + (r & 7); nb = r >> 3; }
  else            { int r = bid - 1728;             mb = 288 + (r & 1); nb = r >> 1; }
  int tid = threadIdx.x, lane = tid & 63, w = tid >> 6;
  int wnA = w >> 2;   // 0..1 : weight half (128 n-rows)
  int wmB = w & 3;    // 0..3 : x quarter (64 m-rows)
  int lm = lane & 15, lq = lane >> 4;

  // staging: wave w covers rows w*32..w*32+31; lane -> (row=l>>2, 16B chunk=(l&3)^s)
  int srow = lane >> 2;
  int schunk = (lane & 3) ^ ((lane >> 3) & 3);   // pre-swizzled source chunk
  const uint16_t* agp = xb   + (size_t)(mb*256 + w*32 + srow)*512 + schunk*8;
  const uint16_t* bgp = wqkv + (size_t)(nb*256 + w*32 + srow)*512 + schunk*8;
  int rc = (lq ^ ((lm >> 1) & 3)) * 8;           // swizzled read chunk

  f32x4 acc[8][4];
#pragma unroll
  for (int a = 0; a < 8; a++)
#pragma unroll
    for (int b = 0; b < 4; b++) acc[a][b] = (f32x4){0.f,0.f,0.f,0.f};

  #define STAGE_QKV(slot, kt) { \
    uint16_t* Ad = &As[(slot)*8192 + (w*32)*32]; \
    uint16_t* Bd = &Bs[(slot)*8192 + (w*32)*32]; \
    GLL(agp + (kt)*32,           Ad); \
    GLL(agp + (kt)*32 + 16*512,  Ad + 16*32); \
    GLL(bgp + (kt)*32,           Bd); \
    GLL(bgp + (kt)*32 + 16*512,  Bd + 16*32); \
  }

  #define COMPUTE_QKV(slot) { \
    const uint16_t* Wb = &Bs[(slot)*8192 + (wnA*128 + lm)*32 + rc]; \
    const uint16_t* Xb = &As[(slot)*8192 + (wmB*64  + lm)*32 + rc]; \
    short8 wf[8], xf[4]; \
    _Pragma("unroll") \
    for (int na = 0; na < 8; na++) wf[na] = *(const short8*)&Wb[na*16*32]; \
    _Pragma("unroll") \
    for (int mt = 0; mt < 4; mt++) xf[mt] = *(const short8*)&Xb[mt*16*32]; \
    __builtin_amdgcn_s_setprio(1); \
    _Pragma("unroll") \
    for (int na = 0; na < 8; na++) \
      _Pragma("unroll") \
      for (int mt = 0; mt < 4; mt++) \
        acc[na][mt] = __builtin_amdgcn_mfma_f32_16x16x32_bf16(wf[na], xf[mt], acc[na][mt], 0, 0, 0); \
    __builtin_amdgcn_s_setprio(0); \
  }

  STAGE_QKV(0, 0);
  STAGE_QKV(1, 1);
  for (int kt = 0; kt < 15; kt++) {
    asm volatile("s_waitcnt vmcnt(4)" ::: "memory");
    __builtin_amdgcn_s_barrier();
    __builtin_amdgcn_sched_barrier(0);
    if (kt < 14) STAGE_QKV((kt + 2) & 3, kt + 2);
    COMPUTE_QKV(kt & 3);
  }
  asm volatile("s_waitcnt vmcnt(0)" ::: "memory");
  __builtin_amdgcn_s_barrier();
  __builtin_amdgcn_sched_barrier(0);
  COMPUTE_QKV(3);   // kt = 15

  #undef STAGE_QKV
  #undef COMPUTE_QKV

  // epilogue: lane = one token, regs = 4 consecutive d -> 8B packed stores
  int which = nb >> 1;   // 0:q 1:k 2:v (256-tiles don't cross 512 boundaries)
  uint16_t* dst = (which == 0) ? qb : (which == 1) ? kb : vb;
#pragma unroll
  for (int mt = 0; mt < 4; mt++) {
    int m = mb*256 + wmB*64 + mt*16 + lm;
    int bw = m / 145, nl = m - bw*145;
    size_t mbase = (size_t)bw*8*9280 + (size_t)nl*64;   // 145*64 = 9280
#pragma unroll
    for (int na = 0; na < 8; na++) {
      int n0 = nb*256 + wnA*128 + na*16 + lq*4;
      float4 b4 = *(const float4*)&bqkv[n0];
      int c = n0 & 511;
      int hh = c >> 6, d0 = c & 63;
      float f0 = acc[na][mt][0] + b4.x;
      float f1 = acc[na][mt][1] + b4.y;
      float f2 = acc[na][mt][2] + b4.z;
      float f3 = acc[na][mt][3] + b4.w;
      uint32_t lo, hi;
      asm("v_cvt_pk_bf16_f32 %0, %1, %2" : "=v"(lo) : "v"(f0), "v"(f1));
      asm("v_cvt_pk_bf16_f32 %0, %1, %2" : "=v"(hi) : "v"(f2), "v"(f3));
      uint2 pk; pk.x = lo; pk.y = hi;
      *(uint2*)(dst + mbase + (size_t)hh*9280 + d0) = pk;
    }
  }
}

// ---------------- attention: S=QK^T (+ltab via C-operand), softmax, P*V ----------------
__global__ __launch_bounds__(256, 3) void attn_kernel(
    const uint16_t* __restrict__ qb, const uint16_t* __restrict__ kb,
    const uint16_t* __restrict__ vb, const float* __restrict__ ltab,
    float* __restrict__ glog, uint16_t* __restrict__ attn_out) {
  __shared__ __align__(16) uint16_t P[80*168];
  __shared__ __align__(16) uint16_t vt[64*168];
  int bid = blockIdx.x;
  int half = bid & 1;
  int h = (bid >> 1) & 7;
  int b_ = bid >> 4;
  int nw = b_ & 3;
  int tid = threadIdx.x, lane = tid & 63, w = tid >> 6;
  int lm = lane & 15, lq = lane >> 4;
  const size_t hbase = ((size_t)(b_*8 + h)) * (145*64);
  const uint16_t* qp = qb + hbase;
  const uint16_t* kp = kb + hbase;
  const uint16_t* vp = vb + hbase;
  const float* ltp = ltab + (size_t)(nw*8 + h)*(145*160);

  for (int c = tid; c < 1160; c += 256) {
    int j = c >> 3, d0 = (c & 7) * 8;
    uint16_t tmp[8];
    *(uint4*)tmp = *(const uint4*)(vp + (size_t)j*64 + d0);
#pragma unroll
    for (int t = 0; t < 8; t++) vt[(d0 + t)*168 + j] = tmp[t];
  }
  for (int c = tid; c < 960; c += 256)
    vt[(c/15)*168 + 145 + (c%15)] = 0;

  for (int ltile = w; ltile < 5; ltile += 4) {
    int gt = half*5 + ltile;
    f32x4 acc[10];
#pragma unroll
    for (int nt = 0; nt < 10; nt++) {
#pragma unroll
      for (int r = 0; r < 4; r++) {
        int i = gt*16 + lq*4 + r; if (i > 144) i = 144;
        acc[nt][r] = 8.0f * ltp[i*160 + nt*16 + lm];
      }
    }
    int iq = gt*16 + lm; if (iq > 144) iq = 144;
#pragma unroll
    for (int ks = 0; ks < 2; ks++) {
      short8 afr = *(const short8*)(qp + (size_t)iq*64 + ks*32 + lq*8);
#pragma unroll
      for (int nt = 0; nt < 10; nt++) {
        int j = nt*16 + lm; if (j > 144) j = 144;
        short8 bfr = *(const short8*)(kp + (size_t)j*64 + ks*32 + lq*8);
        acc[nt] = __builtin_amdgcn_mfma_f32_16x16x32_bf16(afr, bfr, acc[nt], 0, 0, 0);
      }
    }
    if (gt == 9) {
      if (lq == 0) {
#pragma unroll
        for (int nt = 0; nt < 10; nt++) {
          int j = nt*16 + lm;
          if (j < 145)
            glog[(size_t)(b_*8 + h)*145 + j] = acc[nt][0]*0.125f;
        }
      }
    } else {
#pragma unroll
      for (int r = 0; r < 4; r++) {
        int prow = ltile*16 + lq*4 + r;
        float mx = -3.0e38f;
#pragma unroll
        for (int nt = 0; nt < 10; nt++) {
          int j = nt*16 + lm;
          float t = acc[nt][r]*0.125f;
          if (j >= 145) t = -3.0e38f;
          acc[nt][r] = t;
          mx = fmaxf(mx, t);
        }
#pragma unroll
        for (int off = 1; off < 16; off <<= 1) mx = fmaxf(mx, __shfl_xor(mx, off));
        float sum = 0.f;
#pragma unroll
        for (int nt = 0; nt < 10; nt++) {
          int j = nt*16 + lm;
          float p = (j < 145) ? __expf(acc[nt][r] - mx) : 0.f;
          acc[nt][r] = p; sum += p;
        }
#pragma unroll
        for (int off = 1; off < 16; off <<= 1) sum += __shfl_xor(sum, off);
        float rs = __builtin_amdgcn_rcpf(sum);
#pragma unroll
        for (int nt = 0; nt < 10; nt++)
          P[prow*168 + nt*16 + lm] = f2bf(acc[nt][r] * rs);
      }
    }
  }
  __syncthreads();

  int npv = 5 - half;
  f32x4 oacc[5];
#pragma unroll
  for (int mt = 0; mt < 5; mt++) oacc[mt] = (f32x4){0.f,0.f,0.f,0.f};
#pragma unroll
  for (int ks = 0; ks < 5; ks++) {
    short8 bfr = *(const short8*)&vt[(w*16 + lm)*168 + ks*32 + lq*8];
#pragma unroll
    for (int mt = 0; mt < 5; mt++) {
      if (mt < npv) {
        short8 afr = *(const short8*)&P[(mt*16 + lm)*168 + ks*32 + lq*8];
        oacc[mt] = __builtin_amdgcn_mfma_f32_16x16x32_bf16(afr, bfr, oacc[mt], 0, 0, 0);
      }
    }
  }
#pragma unroll
  for (int mt = 0; mt < 5; mt++) {
    if (mt < npv) {
#pragma unroll
      for (int r = 0; r < 4; r++) {
        int i = half*80 + mt*16 + lq*4 + r;
        attn_out[((size_t)b_*145 + i)*512 + h*64 + w*16 + lm] = f2bf(oacc[mt][r]);
      }
    }
  }
}

// ---------------- gx: global-token redistribution (4 waves) ----------------
__global__ __launch_bounds__(256) void gx_kernel(
    const float* __restrict__ glog, const uint16_t* __restrict__ vb,
    uint16_t* __restrict__ attn_out) {
  int bid = blockIdx.x;           // b*8 + h
  int b = bid >> 3, h = bid & 7;
  int tid = threadIdx.x, lane = tid & 63, w = tid >> 6;
  __shared__ float lg[580];
  __shared__ float pl[576];
  __shared__ float sred[8];
  __shared__ float sacc[256];
  for (int t = tid; t < 580; t += 256) {
    int nwi = t / 145, j = t - nwi*145;
    lg[t] = glog[(size_t)((b*4 + nwi)*8 + h)*145 + j];
  }
  __syncthreads();
  float g2 = 0.25f*(lg[144] + lg[289] + lg[434] + lg[579]);
  float mx = g2;
  for (int t = tid; t < 576; t += 256) {
    int nwi = t / 144, j = t - nwi*144;
    mx = fmaxf(mx, lg[nwi*145 + j]);
  }
#pragma unroll
  for (int off = 1; off < 64; off <<= 1) mx = fmaxf(mx, __shfl_xor(mx, off));
  if (lane == 0) sred[w] = mx;
  __syncthreads();
  mx = fmaxf(fmaxf(sred[0], sred[1]), fmaxf(sred[2], sred[3]));
  float sum = 0.f;
  for (int t = tid; t < 576; t += 256) {
    int nwi = t / 144, j = t - nwi*144;
    float p = __expf(lg[nwi*145 + j] - mx);
    pl[t] = p; sum += p;
  }
#pragma unroll
  for (int off = 1; off < 64; off <<= 1) sum += __shfl_xor(sum, off);
  if (lane == 0) sred[4 + w] = sum;
  __syncthreads();
  sum = (sred[4] + sred[5]) + (sred[6] + sred[7]);
  float p2 = __expf(g2 - mx);
  float rs = __builtin_amdgcn_rcpf(sum + p2);
  const uint16_t* vp = vb + (size_t)((b*4 + w)*8 + h)*(145*64);
  float acc = 0.f;
  int d = lane;
#pragma unroll 4
  for (int j = 0; j < 144; j++)
    acc += pl[w*144 + j] * bf2f(vp[j*64 + d]);
  acc += p2 * bf2f(vp[144*64 + d]);
  sacc[tid] = acc;
  __syncthreads();
  if (w == 0) {
    float tot = (sacc[lane] + sacc[64 + lane]) + (sacc[128 + lane] + sacc[192 + lane]);
    uint16_t o = f2bf(tot * rs);
    for (int nwi = 0; nwi < 4; nwi++)
      attn_out[((size_t)(b*4 + nwi)*145 + 144)*512 + h*64 + d] = o;
  }
}

// ---------------- GEMM 2: output projection (swapped + swizzled, same pipeline) ----------------
__global__ __launch_bounds__(512, 2) void gemm_out(
    const uint16_t* __restrict__ A, const uint16_t* __restrict__ wo,
    const float* __restrict__ bo, float* __restrict__ out) {
  __shared__ __align__(16) uint16_t As[4*256*32];
  __shared__ __align__(16) uint16_t Bs[4*256*32];
  int bid = blockIdx.x;
  int mb, nb;
  if (bid < 576) { int g = bid / 16, r = bid % 16; mb = g*8 + (r & 7); nb = r >> 3; }
  else           { int r = bid - 576;              mb = 288 + (r & 1); nb = r >> 1; }
  int tid = threadIdx.x, lane = tid & 63, w = tid >> 6;
  int wnA = w >> 2;   // weight half
  int wmB = w & 3;    // activation quarter
  int lm = lane & 15, lq = lane >> 4;

  int srow = lane >> 2;
  int schunk = (lane & 3) ^ ((lane >> 3) & 3);
  const uint16_t* agp = A  + (size_t)(mb*256 + w*32 + srow)*512 + schunk*8;
  const uint16_t* bgp = wo + (size_t)(nb*256 + w*32 + srow)*512 + schunk*8;
  int rc = (lq ^ ((lm >> 1) & 3)) * 8;

  f32x4 acc[8][4];
#pragma unroll
  for (int a = 0; a < 8; a++)
#pragma unroll
    for (int b = 0; b < 4; b++) acc[a][b] = (f32x4){0.f,0.f,0.f,0.f};

  #define STAGE_O(slot, kt) { \
    uint16_t* Ad = &As[(slot)*8192 + (w*32)*32]; \
    uint16_t* Bd = &Bs[(slot)*8192 + (w*32)*32]; \
    GLL(agp + (kt)*32,           Ad); \
    GLL(agp + (kt)*32 + 16*512,  Ad + 16*32); \
    GLL(bgp + (kt)*32,           Bd); \
    GLL(bgp + (kt)*32 + 16*512,  Bd + 16*32); \
  }

  #define COMPUTE_O(slot) { \
    const uint16_t* Wb = &Bs[(slot)*8192 + (wnA*128 + lm)*32 + rc]; \
    const uint16_t* Xb = &As[(slot)*8192 + (wmB*64  + lm)*32 + rc]; \
    short8 wf[8], xf[4]; \
    _Pragma("unroll") \
    for (int na = 0; na < 8; na++) wf[na] = *(const short8*)&Wb[na*16*32]; \
    _Pragma("unroll") \
    for (int mt = 0; mt < 4; mt++) xf[mt] = *(const short8*)&Xb[mt*16*32]; \
    __builtin_amdgcn_s_setprio(1); \
    _Pragma("unroll") \
    for (int na = 0; na < 8; na++) \
      _Pragma("unroll") \
      for (int mt = 0; mt < 4; mt++) \
        acc[na][mt] = __builtin_amdgcn_mfma_f32_16x16x32_bf16(wf[na], xf[mt], acc[na][mt], 0, 0, 0); \
    __builtin_amdgcn_s_setprio(0); \
  }

  STAGE_O(0, 0);
  STAGE_O(1, 1);
  for (int kt = 0; kt < 15; kt++) {
    asm volatile("s_waitcnt vmcnt(4)" ::: "memory");
    __builtin_amdgcn_s_barrier();
    __builtin_amdgcn_sched_barrier(0);
    if (kt < 14) STAGE_O((kt + 2) & 3, kt + 2);
    COMPUTE_O(kt & 3);
  }
  asm volatile("s_waitcnt vmcnt(0)" ::: "memory");
  __builtin_amdgcn_s_barrier();
  __builtin_amdgcn_sched_barrier(0);
  COMPUTE_O(3);

  #undef STAGE_O
  #undef COMPUTE_O

  // epilogue: lane = one token, regs = 4 consecutive n -> one 16B f32 store/tile
#pragma unroll
  for (int mt = 0; mt < 4; mt++) {
    int m = mb*256 + wmB*64 + mt*16 + lm;
    float* orow = out + (size_t)m*512;
#pragma unroll
    for (int na = 0; na < 8; na++) {
      int n0 = nb*256 + wnA*128 + na*16 + lq*4;
      float4 b4 = *(const float4*)&bo[n0];
      float4 o;
      o.x = acc[na][mt][0] + b4.x;
      o.y = acc[na][mt][1] + b4.y;
      o.z = acc[na][mt][2] + b4.z;
      o.w = acc[na][mt][3] + b4.w;
      *(float4*)(orow + n0) = o;
    }
  }
}

// ---------------- launch ----------------
extern "C" void kernel_launch(void* const* d_in, const int* in_sizes, int n_in,
                              void* d_out, int out_size, void* d_ws, size_t ws_size,
                              hipStream_t stream) {
  const float* x    = (const float*)d_in[0];
  const float* mask = (const float*)d_in[1];
  const float* rpb  = (const float*)d_in[2];
  const float* Wq   = (const float*)d_in[3];
  const float* bq   = (const float*)d_in[4];
  const float* Wk   = (const float*)d_in[5];
  const float* bk   = (const float*)d_in[6];
  const float* Wv   = (const float*)d_in[7];
  const float* bv   = (const float*)d_in[8];
  const float* Wo   = (const float*)d_in[9];
  const float* bo   = (const float*)d_in[10];

  uint8_t* ws = (uint8_t*)d_ws;
  size_t off = 0;
  auto alloc = [&](size_t bytes) -> void* {
    void* p = ws + off; off += (bytes + 255) & ~(size_t)255; return p;
  };
  uint16_t* wqkv   = (uint16_t*)alloc((size_t)1536*512*2);
  uint16_t* wo     = (uint16_t*)alloc((size_t)512*512*2);
  float*    bqkv   = (float*)alloc(1536*4);
  float*    ltab   = (float*)alloc((size_t)4*8*145*160*4);
  float*    glog   = (float*)alloc((size_t)512*8*145*4);
  uint16_t* xb     = (uint16_t*)alloc((size_t)MROWS*512*2);
  uint16_t* qb     = (uint16_t*)alloc((size_t)MROWS*512*2);
  uint16_t* kb     = (uint16_t*)alloc((size_t)MROWS*512*2);
  uint16_t* vb     = (uint16_t*)alloc((size_t)MROWS*512*2);
  uint16_t* attn   = (uint16_t*)alloc((size_t)MROWS*512*2);

  cast_x<<<18560, 256, 0, stream>>>(x, xb);
  prep_kernel<<<7002, 256, 0, stream>>>(rpb, Wq, bq, Wk, bk, Wv, bv, Wo, mask,
                                        wqkv, wo, bqkv, ltab);
  gemm_qkv<<<1740, 512, 0, stream>>>(xb, wqkv, bqkv, qb, kb, vb);
  attn_kernel<<<8192, 256, 0, stream>>>(qb, kb, vb, ltab, glog, attn);
  gx_kernel<<<1024, 256, 0, stream>>>(glog, vb, attn);
  gemm_out<<<580, 512, 0, stream>>>(attn, wo, bo, (float*)d_out);
}